// Round 1
// baseline (71.495 us; speedup 1.0000x reference)
//
#include <hip/hip_runtime.h>

#define NI 65536
#define NO 65536
#define NW 32
#define NB 32

// Prep: transpose x (B=32, I) -> xT (I, 32) and fwm = fw * fm elementwise.
__global__ __launch_bounds__(256) void dsm_prep(
    const float* __restrict__ x,
    const float* __restrict__ fw,
    const float* __restrict__ fm,
    float* __restrict__ xT,
    float* __restrict__ fwm,
    int mode)
{
    __shared__ float tile[32][33];
    const int tid = threadIdx.x;
    const int tx = tid & 31;
    const int ty = tid >> 5;          // 0..7
    const int i0 = blockIdx.x * 32;

    if (mode >= 1) {
#pragma unroll
        for (int r = 0; r < 4; ++r) {
            const int b = ty + 8 * r;
            tile[b][tx] = x[(size_t)b * NI + i0 + tx];
        }
        __syncthreads();
#pragma unroll
        for (int r = 0; r < 4; ++r) {
            const int ii = ty + 8 * r;
            xT[(size_t)(i0 + ii) * NB + tx] = tile[tx][ii];
        }
    }
    if (mode >= 2) {
        // 2048 blocks * 1024 floats = 2M = NI*NW
        const size_t base = (size_t)blockIdx.x * 1024 + (size_t)tid * 4;
        const float4 a = *(const float4*)(fw + base);
        const float4 m = *(const float4*)(fm + base);
        float4 r4;
        r4.x = a.x * m.x; r4.y = a.y * m.y;
        r4.z = a.z * m.z; r4.w = a.w * m.w;
        *(float4*)(fwm + base) = r4;
    }
}

// Main: each 32-lane half-wave computes one output column o (all 32 b's),
// 4 o's sequentially; block covers 32 o's. Output staged via LDS for
// coalesced (B, O) row-major stores.
template<int MODE>   // 2: xT+fwm, 1: xT only, 0: no workspace (slow fallback)
__global__ __launch_bounds__(256) void dsm_main(
    const float* __restrict__ x,
    const float* __restrict__ fw,
    const float* __restrict__ fm,
    const int*   __restrict__ om,
    const float* __restrict__ rm,
    const float* __restrict__ xT,
    const float* __restrict__ fwm,
    float* __restrict__ out)
{
    __shared__ float tile[32][33];
    const int tid = threadIdx.x;
    const int l  = tid & 31;          // b lane
    const int hw = tid >> 5;          // half-wave id 0..7
    const int o_base = blockIdx.x * 32;

#pragma unroll
    for (int k = 0; k < 4; ++k) {
        const int o = o_base + hw * 4 + k;
        const int i_l = om[(size_t)o * NW + l];       // lane l holds i for w=l
        float s_l;
        if (MODE == 2) {
            s_l = fwm[(size_t)i_l * NW + l] * rm[(size_t)o * NW + l];
        } else {
            s_l = fw[(size_t)i_l * NW + l] * fm[(size_t)i_l * NW + l]
                * rm[(size_t)o * NW + l];
        }
        float acc = 0.f;
#pragma unroll
        for (int w = 0; w < NW; ++w) {
            const int   i = __shfl(i_l, w, 32);
            const float s = __shfl(s_l, w, 32);
            float xv;
            if (MODE >= 1) xv = xT[(size_t)i * NB + l];     // 128B coalesced
            else           xv = x[(size_t)l * NI + i];      // strided fallback
            acc = fmaf(s, xv, acc);
        }
        tile[l][hw * 4 + k] = acc;
    }
    __syncthreads();
#pragma unroll
    for (int r = 0; r < 4; ++r) {
        const int b = (tid >> 5) + 8 * r;
        out[(size_t)b * NO + o_base + (tid & 31)] = tile[b][tid & 31];
    }
}

extern "C" void kernel_launch(void* const* d_in, const int* in_sizes, int n_in,
                              void* d_out, int out_size, void* d_ws, size_t ws_size,
                              hipStream_t stream) {
    const float* x  = (const float*)d_in[0];
    const float* fw = (const float*)d_in[1];
    const float* fm = (const float*)d_in[2];
    const int*   om = (const int*)d_in[3];
    const float* rm = (const float*)d_in[4];
    float* out = (float*)d_out;

    float* xT  = (float*)d_ws;
    float* fwm = xT + (size_t)NI * NB;

    const size_t need1 = (size_t)NI * NB * sizeof(float);   // 8 MB
    int mode = 0;
    if (ws_size >= 2 * need1)      mode = 2;
    else if (ws_size >= need1)     mode = 1;

    if (mode >= 1)
        dsm_prep<<<dim3(NI / 32), 256, 0, stream>>>(x, fw, fm, xT, fwm, mode);

    dim3 grid(NO / 32);
    if (mode == 2)
        dsm_main<2><<<grid, 256, 0, stream>>>(x, fw, fm, om, rm, xT, fwm, out);
    else if (mode == 1)
        dsm_main<1><<<grid, 256, 0, stream>>>(x, fw, fm, om, rm, xT, fwm, out);
    else
        dsm_main<0><<<grid, 256, 0, stream>>>(x, fw, fm, om, rm, xT, fwm, out);
}

// Round 2
// 46.451 us; speedup vs baseline: 1.5391x; 1.5391x over previous
//
#include <hip/hip_runtime.h>
#include <hip/hip_fp16.h>

#define NI 65536
#define NO 65536
#define NW 32
#define NB 32

// ---- kernel 1: transpose x (B,I) -> xTh fp16 [I][NB]; fwmh = fp16(fw*fm) ----
__global__ __launch_bounds__(256) void dsm_prep(
    const float* __restrict__ x, const float* __restrict__ fw,
    const float* __restrict__ fm, ushort* __restrict__ xTh,
    ushort* __restrict__ fwmh)
{
    __shared__ float tile[32][33];
    const int tid = threadIdx.x;
    const int tx = tid & 31, ty = tid >> 5;
    const int i0 = blockIdx.x * 32;
#pragma unroll
    for (int r = 0; r < 4; ++r) {
        const int b = ty + 8 * r;
        tile[b][tx] = x[(size_t)b * NI + i0 + tx];
    }
    __syncthreads();
#pragma unroll
    for (int r = 0; r < 4; ++r) {
        const int ii = ty + 8 * r;
        xTh[(size_t)(i0 + ii) * NB + tx] =
            __half_as_ushort(__float2half(tile[tx][ii]));
    }
    // fw*fm -> fp16, 2048 blocks * 1024 elems = NI*NW
    const size_t base = (size_t)blockIdx.x * 1024 + (size_t)tid * 4;
    const float4 a = *(const float4*)(fw + base);
    const float4 m = *(const float4*)(fm + base);
    ushort4 h;
    h.x = __half_as_ushort(__float2half(a.x * m.x));
    h.y = __half_as_ushort(__float2half(a.y * m.y));
    h.z = __half_as_ushort(__float2half(a.z * m.z));
    h.w = __half_as_ushort(__float2half(a.w * m.w));
    *(ushort4*)(fwmh + base) = h;
}

// ---- kernel 2: P[o][w] = (i << 16) | fp16( fwmh[i][w] * rm[o][w] ) ----
__global__ __launch_bounds__(256) void dsm_pack(
    const int* __restrict__ om, const float* __restrict__ rm,
    const ushort* __restrict__ fwmh, uint* __restrict__ P)
{
    const size_t base = ((size_t)blockIdx.x * 256 + threadIdx.x) * 4;
    const int4  iv = *(const int4*)(om + base);
    const float4 rv = *(const float4*)(rm + base);
    const int w0 = (int)(base & 31);
    const int   ia[4] = {iv.x, iv.y, iv.z, iv.w};
    const float ra[4] = {rv.x, rv.y, rv.z, rv.w};
    uint4 pv;
    uint* pp = (uint*)&pv;
#pragma unroll
    for (int j = 0; j < 4; ++j) {
        const uint i = (uint)ia[j] & 0xffffu;
        const float fv = __half2float(__ushort_as_half(fwmh[i * NW + w0 + j]));
        const float s = fv * ra[j];
        pp[j] = (i << 16) | (uint)__half_as_ushort(__float2half(s));
    }
    *(uint4*)(P + base) = pv;
}

// ---- kernel 3: main. wave handles 8 o's; lane = 8*g + c; lane covers b=4c..4c+3
__global__ __launch_bounds__(256) void dsm_main(
    const ushort* __restrict__ xTh,   // fp16 [NI][NB]
    const uint*   __restrict__ P,     // [NO][NW] packed (i<<16 | h(s))
    float* __restrict__ out)          // [NB][NO]
{
    __shared__ uint sp[4][264];       // per-wave 8 o's, stride 33 (pad)
    const int tid = threadIdx.x;
    const int wave = tid >> 6;
    const int lane = tid & 63;
    const int g = lane >> 3;          // o sub-index within wave
    const int c = lane & 7;           // b-group: b = 4c..4c+3
    const int o_block = blockIdx.x * 32;
    const int o_wave = o_block + wave * 8;

    // stage packed (i,s) rows for this wave's 8 o's into padded LDS
    {
        const uint4 pv = *(const uint4*)(P + (size_t)o_wave * NW + lane * 4);
        const uint* pq = (const uint*)&pv;
        const int lin = lane * 4;
#pragma unroll
        for (int j = 0; j < 4; ++j) {
            const int ol = (lin + j) >> 5, w = (lin + j) & 31;
            sp[wave][ol * 33 + w] = pq[j];
        }
    }
    __syncthreads();

    float acc0 = 0.f, acc1 = 0.f, acc2 = 0.f, acc3 = 0.f;
    const uint* spw = &sp[wave][g * 33];
#pragma unroll
    for (int w = 0; w < NW; ++w) {
        const uint p = spw[w];                      // broadcast, conflict-free
        const uint i = p >> 16;
        const float s = __half2float(__ushort_as_half((ushort)p));
        const uint2 xv = *(const uint2*)(xTh + i * NB + c * 4);  // 8B/lane
        const float x0 = __half2float(__ushort_as_half((ushort)(xv.x & 0xffffu)));
        const float x1 = __half2float(__ushort_as_half((ushort)(xv.x >> 16)));
        const float x2 = __half2float(__ushort_as_half((ushort)(xv.y & 0xffffu)));
        const float x3 = __half2float(__ushort_as_half((ushort)(xv.y >> 16)));
        acc0 = fmaf(s, x0, acc0);
        acc1 = fmaf(s, x1, acc1);
        acc2 = fmaf(s, x2, acc2);
        acc3 = fmaf(s, x3, acc3);
    }
    __syncthreads();                  // done reading sp; reuse as out tile

    float* tile = (float*)sp;         // [32][33]
    const int ocol = wave * 8 + g;
    tile[(4 * c + 0) * 33 + ocol] = acc0;
    tile[(4 * c + 1) * 33 + ocol] = acc1;
    tile[(4 * c + 2) * 33 + ocol] = acc2;
    tile[(4 * c + 3) * 33 + ocol] = acc3;
    __syncthreads();
#pragma unroll
    for (int r = 0; r < 4; ++r) {
        const int b = (tid >> 5) + 8 * r;
        out[(size_t)b * NO + o_block + (tid & 31)] = tile[b * 33 + (tid & 31)];
    }
}

// ---- fallback (no workspace): direct fp32, half-wave per o ----
__global__ __launch_bounds__(256) void dsm_fallback(
    const float* __restrict__ x, const float* __restrict__ fw,
    const float* __restrict__ fm, const int* __restrict__ om,
    const float* __restrict__ rm, float* __restrict__ out)
{
    const int tid = threadIdx.x;
    const int l = tid & 31, hw = tid >> 5;
    const int o = blockIdx.x * 8 + hw;
    const int i_l = om[(size_t)o * NW + l];
    const float s_l = fw[(size_t)i_l * NW + l] * fm[(size_t)i_l * NW + l]
                    * rm[(size_t)o * NW + l];
    float acc = 0.f;
#pragma unroll
    for (int w = 0; w < NW; ++w) {
        const int   i = __shfl(i_l, w, 32);
        const float s = __shfl(s_l, w, 32);
        acc = fmaf(s, x[(size_t)l * NI + i], acc);
    }
    out[(size_t)l * NO + o] = acc;
}

extern "C" void kernel_launch(void* const* d_in, const int* in_sizes, int n_in,
                              void* d_out, int out_size, void* d_ws, size_t ws_size,
                              hipStream_t stream) {
    const float* x  = (const float*)d_in[0];
    const float* fw = (const float*)d_in[1];
    const float* fm = (const float*)d_in[2];
    const int*   om = (const int*)d_in[3];
    const float* rm = (const float*)d_in[4];
    float* out = (float*)d_out;

    const size_t needP  = (size_t)NO * NW * sizeof(uint);    // 8 MB
    const size_t needXT = (size_t)NI * NB * sizeof(ushort);  // 4 MB
    const size_t needFW = (size_t)NI * NW * sizeof(ushort);  // 4 MB

    if (ws_size >= needP + needXT + needFW) {
        uint*   P    = (uint*)d_ws;
        ushort* xTh  = (ushort*)((char*)d_ws + needP);
        ushort* fwmh = (ushort*)((char*)d_ws + needP + needXT);
        dsm_prep<<<dim3(NI / 32), 256, 0, stream>>>(x, fw, fm, xTh, fwmh);
        dsm_pack<<<dim3(NO * NW / 1024), 256, 0, stream>>>(om, rm, fwmh, P);
        dsm_main<<<dim3(NO / 32), 256, 0, stream>>>(xTh, P, out);
    } else {
        dsm_fallback<<<dim3(NO / 8), 256, 0, stream>>>(x, fw, fm, om, rm, out);
    }
}

// Round 4
// 45.709 us; speedup vs baseline: 1.5641x; 1.0162x over previous
//
#include <hip/hip_runtime.h>
#include <hip/hip_fp16.h>

#define NI 65536
#define NO 65536
#define NW 32
#define NB 32

typedef float  fx4 __attribute__((ext_vector_type(4)));
typedef int    ix4 __attribute__((ext_vector_type(4)));
typedef uint   ux4 __attribute__((ext_vector_type(4)));
typedef uint   ux2 __attribute__((ext_vector_type(2)));
typedef ushort sx4 __attribute__((ext_vector_type(4)));

// ---- kernel 1: transpose x (B,I) -> xTh fp16 [I][NB]; fwmh = fp16(fw*fm) ----
__global__ __launch_bounds__(256) void dsm_prep(
    const float* __restrict__ x, const float* __restrict__ fw,
    const float* __restrict__ fm, ushort* __restrict__ xTh,
    ushort* __restrict__ fwmh)
{
    __shared__ float tile[32][33];
    const int tid = threadIdx.x;
    const int tx = tid & 31, ty = tid >> 5;
    const int i0 = blockIdx.x * 32;
#pragma unroll
    for (int r = 0; r < 4; ++r) {
        const int b = ty + 8 * r;
        tile[b][tx] = __builtin_nontemporal_load(&x[(size_t)b * NI + i0 + tx]);
    }
    __syncthreads();
#pragma unroll
    for (int r = 0; r < 4; ++r) {
        const int ii = ty + 8 * r;
        xTh[(size_t)(i0 + ii) * NB + tx] =
            __half_as_ushort(__float2half(tile[tx][ii]));
    }
    // fw*fm -> fp16, 2048 blocks * 1024 elems = NI*NW
    const size_t base = (size_t)blockIdx.x * 1024 + (size_t)tid * 4;
    const fx4 a = __builtin_nontemporal_load((const fx4*)(fw + base));
    const fx4 m = __builtin_nontemporal_load((const fx4*)(fm + base));
    sx4 h;
    h.x = __half_as_ushort(__float2half(a.x * m.x));
    h.y = __half_as_ushort(__float2half(a.y * m.y));
    h.z = __half_as_ushort(__float2half(a.z * m.z));
    h.w = __half_as_ushort(__float2half(a.w * m.w));
    *(sx4*)(fwmh + base) = h;
}

// ---- kernel 2: P[o][w] = (i << 16) | fp16( fwmh[i][w] * rm[o][w] ) ----
__global__ __launch_bounds__(256) void dsm_pack(
    const int* __restrict__ om, const float* __restrict__ rm,
    const ushort* __restrict__ fwmh, uint* __restrict__ P)
{
    const size_t base = ((size_t)blockIdx.x * 256 + threadIdx.x) * 4;
    const ix4 iv = __builtin_nontemporal_load((const ix4*)(om + base));
    const fx4 rv = __builtin_nontemporal_load((const fx4*)(rm + base));
    const int w0 = (int)(base & 31);
    const int   ia[4] = {iv.x, iv.y, iv.z, iv.w};
    const float ra[4] = {rv.x, rv.y, rv.z, rv.w};
    ux4 pv;
#pragma unroll
    for (int j = 0; j < 4; ++j) {
        const uint i = (uint)ia[j] & 0xffffu;
        const float fv = __half2float(__ushort_as_half(fwmh[i * NW + w0 + j]));
        const float s = fv * ra[j];
        pv[j] = (i << 16) | (uint)__half_as_ushort(__float2half(s));
    }
    __builtin_nontemporal_store(pv, (ux4*)(P + base));
}

// ---- kernel 3: main. wave handles 8 o's; lane = 8*g + c; lane covers b=4c..4c+3
__global__ __launch_bounds__(256) void dsm_main(
    const ushort* __restrict__ xTh,   // fp16 [NI][NB]
    const uint*   __restrict__ P,     // [NO][NW] packed (i<<16 | h(s))
    float* __restrict__ out)          // [NB][NO]
{
    __shared__ uint sp[4][264];       // per-wave 8 o's, stride 33 (pad)
    const int tid = threadIdx.x;
    const int wave = tid >> 6;
    const int lane = tid & 63;
    const int g = lane >> 3;          // o sub-index within wave
    const int c = lane & 7;           // b-group: b = 4c..4c+3
    const int o_block = blockIdx.x * 32;
    const int o_wave = o_block + wave * 8;

    // stage packed (i,s) rows for this wave's 8 o's into padded LDS
    {
        const ux4 pv = __builtin_nontemporal_load(
            (const ux4*)(P + (size_t)o_wave * NW + lane * 4));
        const int lin = lane * 4;
#pragma unroll
        for (int j = 0; j < 4; ++j) {
            const int ol = (lin + j) >> 5, w = (lin + j) & 31;
            sp[wave][ol * 33 + w] = pv[j];
        }
    }
    __syncthreads();

    float acc0 = 0.f, acc1 = 0.f, acc2 = 0.f, acc3 = 0.f;
    const uint* spw = &sp[wave][g * 33];
#pragma unroll
    for (int w = 0; w < NW; ++w) {
        const uint p = spw[w];                      // broadcast, conflict-free
        const uint i = p >> 16;
        const float s = __half2float(__ushort_as_half((ushort)p));
        const ux2 xv = *(const ux2*)(xTh + i * NB + c * 4);  // 8B/lane
        const float x0 = __half2float(__ushort_as_half((ushort)(xv.x & 0xffffu)));
        const float x1 = __half2float(__ushort_as_half((ushort)(xv.x >> 16)));
        const float x2 = __half2float(__ushort_as_half((ushort)(xv.y & 0xffffu)));
        const float x3 = __half2float(__ushort_as_half((ushort)(xv.y >> 16)));
        acc0 = fmaf(s, x0, acc0);
        acc1 = fmaf(s, x1, acc1);
        acc2 = fmaf(s, x2, acc2);
        acc3 = fmaf(s, x3, acc3);
    }
    __syncthreads();                  // done reading sp; reuse as out tile

    float* tile = (float*)sp;         // [32][33]
    const int ocol = wave * 8 + g;
    tile[(4 * c + 0) * 33 + ocol] = acc0;
    tile[(4 * c + 1) * 33 + ocol] = acc1;
    tile[(4 * c + 2) * 33 + ocol] = acc2;
    tile[(4 * c + 3) * 33 + ocol] = acc3;
    __syncthreads();
#pragma unroll
    for (int r = 0; r < 4; ++r) {
        const int b = (tid >> 5) + 8 * r;
        __builtin_nontemporal_store(tile[b * 33 + (tid & 31)],
                                    &out[(size_t)b * NO + o_block + (tid & 31)]);
    }
}

// ---- fallback (no workspace): direct fp32, half-wave per o ----
__global__ __launch_bounds__(256) void dsm_fallback(
    const float* __restrict__ x, const float* __restrict__ fw,
    const float* __restrict__ fm, const int* __restrict__ om,
    const float* __restrict__ rm, float* __restrict__ out)
{
    const int tid = threadIdx.x;
    const int l = tid & 31, hw = tid >> 5;
    const int o = blockIdx.x * 8 + hw;
    const int i_l = om[(size_t)o * NW + l];
    const float s_l = fw[(size_t)i_l * NW + l] * fm[(size_t)i_l * NW + l]
                    * rm[(size_t)o * NW + l];
    float acc = 0.f;
#pragma unroll
    for (int w = 0; w < NW; ++w) {
        const int   i = __shfl(i_l, w, 32);
        const float s = __shfl(s_l, w, 32);
        acc = fmaf(s, x[(size_t)l * NI + i], acc);
    }
    out[(size_t)l * NO + o] = acc;
}

extern "C" void kernel_launch(void* const* d_in, const int* in_sizes, int n_in,
                              void* d_out, int out_size, void* d_ws, size_t ws_size,
                              hipStream_t stream) {
    const float* x  = (const float*)d_in[0];
    const float* fw = (const float*)d_in[1];
    const float* fm = (const float*)d_in[2];
    const int*   om = (const int*)d_in[3];
    const float* rm = (const float*)d_in[4];
    float* out = (float*)d_out;

    const size_t needP  = (size_t)NO * NW * sizeof(uint);    // 8 MB
    const size_t needXT = (size_t)NI * NB * sizeof(ushort);  // 4 MB
    const size_t needFW = (size_t)NI * NW * sizeof(ushort);  // 4 MB

    if (ws_size >= needP + needXT + needFW) {
        uint*   P    = (uint*)d_ws;
        ushort* xTh  = (ushort*)((char*)d_ws + needP);
        ushort* fwmh = (ushort*)((char*)d_ws + needP + needXT);
        dsm_prep<<<dim3(NI / 32), 256, 0, stream>>>(x, fw, fm, xTh, fwmh);
        dsm_pack<<<dim3(NO * NW / 1024), 256, 0, stream>>>(om, rm, fwmh, P);
        dsm_main<<<dim3(NO / 32), 256, 0, stream>>>(xTh, P, out);
    } else {
        dsm_fallback<<<dim3(NO / 8), 256, 0, stream>>>(x, fw, fm, om, rm, out);
    }
}